// Round 1
// baseline (465.135 us; speedup 1.0000x reference)
//
#include <hip/hip_runtime.h>

// Problem constants
#define Bn 8
#define Tn 2048
#define En 512
#define Hn 16
#define Dn 32
#define NC 32          // scan chunks
#define CL 64          // chunk length (Tn/NC)
#define INV_DECAY (1.0f/1.2f)

// ---------------- K1: h = x @ W + b  (fp32 LDS-tiled GEMM) ----------------
// M=16384, N=512, K=512. BM=BN=64, BK=16, 256 threads, 4x4 micro-tile.
#define BM 64
#define BN 64
#define BK 16
__global__ __launch_bounds__(256) void gemm_k(const float* __restrict__ x,
                                              const float* __restrict__ W,
                                              const float* __restrict__ bias,
                                              float* __restrict__ h) {
    __shared__ float As[BK][BM + 4];   // +4 pad: rows 272B (16B aligned), spreads banks
    __shared__ float Bs[BK][BN];
    const int bm = blockIdx.x, bn = blockIdx.y;
    const int tid = threadIdx.x;
    const int tx = tid & 15, ty = tid >> 4;
    const int m0 = bm * BM, n0 = bn * BN;

    // load mappings
    const int la_m = tid >> 2;          // 0..63
    const int la_k = (tid & 3) * 4;     // 0,4,8,12
    const int lb_k = tid >> 4;          // 0..15
    const int lb_n = (tid & 15) * 4;    // 0..60

    float acc[4][4] = {};

    for (int k0 = 0; k0 < En; k0 += BK) {
        float4 av = *reinterpret_cast<const float4*>(&x[(size_t)(m0 + la_m) * En + k0 + la_k]);
        float4 bv = *reinterpret_cast<const float4*>(&W[(size_t)(k0 + lb_k) * En + n0 + lb_n]);
        __syncthreads();
        As[la_k + 0][la_m] = av.x;
        As[la_k + 1][la_m] = av.y;
        As[la_k + 2][la_m] = av.z;
        As[la_k + 3][la_m] = av.w;
        *reinterpret_cast<float4*>(&Bs[lb_k][lb_n]) = bv;
        __syncthreads();
        #pragma unroll
        for (int k = 0; k < BK; k++) {
            float4 a = *reinterpret_cast<const float4*>(&As[k][ty * 4]);
            float4 b = *reinterpret_cast<const float4*>(&Bs[k][tx * 4]);
            acc[0][0] += a.x * b.x; acc[0][1] += a.x * b.y; acc[0][2] += a.x * b.z; acc[0][3] += a.x * b.w;
            acc[1][0] += a.y * b.x; acc[1][1] += a.y * b.y; acc[1][2] += a.y * b.z; acc[1][3] += a.y * b.w;
            acc[2][0] += a.z * b.x; acc[2][1] += a.z * b.y; acc[2][2] += a.z * b.z; acc[2][3] += a.z * b.w;
            acc[3][0] += a.w * b.x; acc[3][1] += a.w * b.y; acc[3][2] += a.w * b.z; acc[3][3] += a.w * b.w;
        }
    }
    float4 bv4 = *reinterpret_cast<const float4*>(&bias[n0 + tx * 4]);
    #pragma unroll
    for (int i = 0; i < 4; i++) {
        float4 o;
        o.x = acc[i][0] + bv4.x; o.y = acc[i][1] + bv4.y;
        o.z = acc[i][2] + bv4.z; o.w = acc[i][3] + bv4.w;
        *reinterpret_cast<float4*>(&h[(size_t)(m0 + ty * 4 + i) * En + n0 + tx * 4]) = o;
    }
}

// ---------------- K2a: per-chunk local decayed sums ----------------
// locals[b][c][e] = scan over chunk starting from 0
__global__ __launch_bounds__(512) void scan_local_k(const float* __restrict__ h,
                                                    float* __restrict__ locals) {
    const int c = blockIdx.x, b = blockIdx.y;
    const int e = threadIdx.x;
    const float* hp = h + ((size_t)(b * Tn + c * CL)) * En + e;
    float s = 0.f;
    for (int t = 0; t < CL; t++) s = (s + hp[(size_t)t * En]) * INV_DECAY;
    locals[(size_t)(b * NC + c) * En + e] = s;
}

// ---------------- K2b: serial prefix over chunks ----------------
// Acar[b][c][e] = S at token c*CL (state entering chunk c)
__global__ __launch_bounds__(512) void scan_prefix_k(const float* __restrict__ locals,
                                                     float* __restrict__ Acar) {
    const int b = blockIdx.x;
    const int e = threadIdx.x;
    float invRL = 1.f;
    #pragma unroll
    for (int i = 0; i < CL; i++) invRL *= INV_DECAY;   // 1/1.2^64 (const-folded)
    float A = 0.f;
    for (int c = 0; c < NC; c++) {
        Acar[(size_t)(b * NC + c) * En + e] = A;
        A = A * invRL + locals[(size_t)(b * NC + c) * En + e];
    }
}

// ---------------- K3: bilinear + residual, S recomputed in LDS ----------------
// grid (c=NC, hd=H, b=B); 256 threads; thread -> (k = tid>>3, i0 = (tid&7)*4)
// Each thread holds C[hd][k][i0..i0+3][0..31] = 128 floats in registers.
// Writes y over h in place (y_pre for LN).
__global__ __launch_bounds__(256) void bilinear_k(float* __restrict__ hio,
                                                  const float* __restrict__ Acar,
                                                  const float* __restrict__ C) {
    const int c = blockIdx.x, hd = blockIdx.y, b = blockIdx.z;
    const int tid = threadIdx.x;
    const int k = tid >> 3, sub = tid & 7;

    __shared__ float hs[CL][Dn];
    __shared__ float Ss[CL][Dn];
    __shared__ float ys[CL][Dn];

    // register-resident C slice: creg[p*8+jq] = C[hd][k][i0+p][jq*4 .. +3]
    float4 creg[32];
    const float4* cp4 = reinterpret_cast<const float4*>(C + (size_t)hd * Dn * Dn * Dn) + (size_t)tid * 32;
    #pragma unroll
    for (int q = 0; q < 32; q++) creg[q] = cp4[q];

    // stage all 64 h rows (this head's 32 channels per token)
    const size_t rowbase = (size_t)(b * Tn + c * CL);
    #pragma unroll
    for (int q = 0; q < 8; q++) {
        int idx = q * 256 + tid;
        int tok = idx >> 5, dd = idx & 31;
        hs[tok][dd] = hio[(rowbase + tok) * En + hd * Dn + dd];
    }
    __syncthreads();

    // sequential in-chunk scan from carry (32 lanes)
    if (tid < Dn) {
        float s = Acar[(size_t)(b * NC + c) * En + hd * Dn + tid];
        for (int t = 0; t < CL; t++) {
            Ss[t][tid] = s;
            s = (s + hs[t][tid]) * INV_DECAY;
        }
    }
    __syncthreads();

    // bilinear per token
    for (int tt = 0; tt < CL; tt++) {
        float4 hv = *reinterpret_cast<const float4*>(&hs[tt][sub * 4]);
        float tmp0 = 0.f, tmp1 = 0.f, tmp2 = 0.f, tmp3 = 0.f;
        #pragma unroll
        for (int jq = 0; jq < 8; jq++) {
            float4 sv = *reinterpret_cast<const float4*>(&Ss[tt][jq * 4]);
            tmp0 += sv.x * creg[jq].x      + sv.y * creg[jq].y      + sv.z * creg[jq].z      + sv.w * creg[jq].w;
            tmp1 += sv.x * creg[8 + jq].x  + sv.y * creg[8 + jq].y  + sv.z * creg[8 + jq].z  + sv.w * creg[8 + jq].w;
            tmp2 += sv.x * creg[16 + jq].x + sv.y * creg[16 + jq].y + sv.z * creg[16 + jq].z + sv.w * creg[16 + jq].w;
            tmp3 += sv.x * creg[24 + jq].x + sv.y * creg[24 + jq].y + sv.z * creg[24 + jq].z + sv.w * creg[24 + jq].w;
        }
        float acc = hv.x * tmp0 + hv.y * tmp1 + hv.z * tmp2 + hv.w * tmp3;
        acc += __shfl_xor(acc, 1);
        acc += __shfl_xor(acc, 2);
        acc += __shfl_xor(acc, 4);
        if (sub == 0) ys[tt][k] = acc + hs[tt][k];
    }
    __syncthreads();

    // write back (in place over h)
    #pragma unroll
    for (int q = 0; q < 8; q++) {
        int idx = q * 256 + tid;
        int tok = idx >> 5, dd = idx & 31;
        hio[(rowbase + tok) * En + hd * Dn + dd] = ys[tok][dd];
    }
}

// ---------------- K4: LayerNorm over E=512, one wave per row ----------------
__global__ __launch_bounds__(256) void ln_k(const float* __restrict__ y,
                                            const float* __restrict__ gamma,
                                            const float* __restrict__ beta,
                                            float* __restrict__ out) {
    const int row = blockIdx.x * 4 + (threadIdx.x >> 6);
    const int lane = threadIdx.x & 63;
    const float* yp = y + (size_t)row * En;
    float4 v0 = reinterpret_cast<const float4*>(yp)[lane * 2];
    float4 v1 = reinterpret_cast<const float4*>(yp)[lane * 2 + 1];
    float s  = v0.x + v0.y + v0.z + v0.w + v1.x + v1.y + v1.z + v1.w;
    float s2 = v0.x*v0.x + v0.y*v0.y + v0.z*v0.z + v0.w*v0.w
             + v1.x*v1.x + v1.y*v1.y + v1.z*v1.z + v1.w*v1.w;
    #pragma unroll
    for (int off = 1; off < 64; off <<= 1) {
        s  += __shfl_xor(s, off);
        s2 += __shfl_xor(s2, off);
    }
    const float mu = s * (1.f / En);
    const float var = s2 * (1.f / En) - mu * mu;
    const float rs = rsqrtf(var + 1e-3f);
    const int cbase = lane * 8;
    float4 g0 = reinterpret_cast<const float4*>(&gamma[cbase])[0];
    float4 g1 = reinterpret_cast<const float4*>(&gamma[cbase])[1];
    float4 b0 = reinterpret_cast<const float4*>(&beta[cbase])[0];
    float4 b1 = reinterpret_cast<const float4*>(&beta[cbase])[1];
    float4 o0, o1;
    o0.x = (v0.x - mu) * rs * g0.x + b0.x; o0.y = (v0.y - mu) * rs * g0.y + b0.y;
    o0.z = (v0.z - mu) * rs * g0.z + b0.z; o0.w = (v0.w - mu) * rs * g0.w + b0.w;
    o1.x = (v1.x - mu) * rs * g1.x + b1.x; o1.y = (v1.y - mu) * rs * g1.y + b1.y;
    o1.z = (v1.z - mu) * rs * g1.z + b1.z; o1.w = (v1.w - mu) * rs * g1.w + b1.w;
    float* op = out + (size_t)row * En;
    reinterpret_cast<float4*>(op)[lane * 2]     = o0;
    reinterpret_cast<float4*>(op)[lane * 2 + 1] = o1;
}

extern "C" void kernel_launch(void* const* d_in, const int* in_sizes, int n_in,
                              void* d_out, int out_size, void* d_ws, size_t ws_size,
                              hipStream_t stream) {
    const float* x     = (const float*)d_in[0];
    const float* W     = (const float*)d_in[1];
    const float* bias  = (const float*)d_in[2];
    const float* C     = (const float*)d_in[3];
    const float* gamma = (const float*)d_in[4];
    const float* beta  = (const float*)d_in[5];
    float* out = (float*)d_out;

    // workspace layout (floats): h[16384*512] | locals[B*NC*E] | Acar[B*NC*E]
    float* hbuf   = (float*)d_ws;
    float* locals = hbuf + (size_t)Bn * Tn * En;
    float* Acar   = locals + (size_t)Bn * NC * En;
    // total: 33.55MB + 2*0.52MB = ~34.6MB

    gemm_k<<<dim3((Bn * Tn) / BM, En / BN), 256, 0, stream>>>(x, W, bias, hbuf);
    scan_local_k<<<dim3(NC, Bn), 512, 0, stream>>>(hbuf, locals);
    scan_prefix_k<<<Bn, 512, 0, stream>>>(locals, Acar);
    bilinear_k<<<dim3(NC, Hn, Bn), 256, 0, stream>>>(hbuf, Acar, C);
    ln_k<<<(Bn * Tn) / 4, 256, 0, stream>>>(hbuf, gamma, beta, out);
}

// Round 2
// 265.985 us; speedup vs baseline: 1.7487x; 1.7487x over previous
//
#include <hip/hip_runtime.h>
#include <hip/hip_bf16.h>

// Problem constants
#define Bn 8
#define Tn 2048
#define En 512
#define Hn 16
#define Dn 32
#define NC 32          // scan chunks
#define CL 64          // chunk length (Tn/NC)
#define TCH 256        // tokens per bilinear block
#define INV_DECAY (1.0f/1.2f)

typedef __attribute__((ext_vector_type(8))) short  bf16x8;  // 8 bf16 (4 VGPRs)
typedef __attribute__((ext_vector_type(4))) float  f32x4;
typedef __attribute__((ext_vector_type(8))) unsigned short u16x8;

__device__ __forceinline__ unsigned short f2b(float f) {
    __hip_bfloat16 h = __float2bfloat16(f);   // RNE
    return *reinterpret_cast<unsigned short*>(&h);
}
__device__ __forceinline__ float b2f(unsigned short u) {
    union { unsigned int i; float f; } c; c.i = ((unsigned int)u) << 16; return c.f;
}

// ---------------- K0: C fp32 -> bf16 (1MB, L2/L3-resident weight for MFMA B) ----
__global__ __launch_bounds__(256) void cvtC_k(const float* __restrict__ C,
                                              unsigned short* __restrict__ Cb) {
    int idx = blockIdx.x * 256 + threadIdx.x;   // 8 elems per thread
    const float4* p = reinterpret_cast<const float4*>(C) + (size_t)idx * 2;
    float4 a = p[0], b = p[1];
    u16x8 st;
    st[0]=f2b(a.x); st[1]=f2b(a.y); st[2]=f2b(a.z); st[3]=f2b(a.w);
    st[4]=f2b(b.x); st[5]=f2b(b.y); st[6]=f2b(b.z); st[7]=f2b(b.w);
    *reinterpret_cast<u16x8*>(Cb + (size_t)idx * 8) = st;
}

// ---------------- K1: h = x @ W + b  (fp32 LDS-tiled GEMM, bf16 output) -------
#define BM 64
#define BN 64
#define BK 16
__global__ __launch_bounds__(256) void gemm_k(const float* __restrict__ x,
                                              const float* __restrict__ W,
                                              const float* __restrict__ bias,
                                              unsigned short* __restrict__ h) {
    __shared__ float As[BK][BM + 4];
    __shared__ float Bs[BK][BN];
    const int bm = blockIdx.x, bn = blockIdx.y;
    const int tid = threadIdx.x;
    const int tx = tid & 15, ty = tid >> 4;
    const int m0 = bm * BM, n0 = bn * BN;

    const int la_m = tid >> 2;
    const int la_k = (tid & 3) * 4;
    const int lb_k = tid >> 4;
    const int lb_n = (tid & 15) * 4;

    float acc[4][4] = {};

    for (int k0 = 0; k0 < En; k0 += BK) {
        float4 av = *reinterpret_cast<const float4*>(&x[(size_t)(m0 + la_m) * En + k0 + la_k]);
        float4 bv = *reinterpret_cast<const float4*>(&W[(size_t)(k0 + lb_k) * En + n0 + lb_n]);
        __syncthreads();
        As[la_k + 0][la_m] = av.x;
        As[la_k + 1][la_m] = av.y;
        As[la_k + 2][la_m] = av.z;
        As[la_k + 3][la_m] = av.w;
        *reinterpret_cast<float4*>(&Bs[lb_k][lb_n]) = bv;
        __syncthreads();
        #pragma unroll
        for (int k = 0; k < BK; k++) {
            float4 a = *reinterpret_cast<const float4*>(&As[k][ty * 4]);
            float4 b = *reinterpret_cast<const float4*>(&Bs[k][tx * 4]);
            acc[0][0] += a.x * b.x; acc[0][1] += a.x * b.y; acc[0][2] += a.x * b.z; acc[0][3] += a.x * b.w;
            acc[1][0] += a.y * b.x; acc[1][1] += a.y * b.y; acc[1][2] += a.y * b.z; acc[1][3] += a.y * b.w;
            acc[2][0] += a.z * b.x; acc[2][1] += a.z * b.y; acc[2][2] += a.z * b.z; acc[2][3] += a.z * b.w;
            acc[3][0] += a.w * b.x; acc[3][1] += a.w * b.y; acc[3][2] += a.w * b.z; acc[3][3] += a.w * b.w;
        }
    }
    float4 bv4 = *reinterpret_cast<const float4*>(&bias[n0 + tx * 4]);
    #pragma unroll
    for (int i = 0; i < 4; i++) {
        ushort4 st;
        st.x = f2b(acc[i][0] + bv4.x); st.y = f2b(acc[i][1] + bv4.y);
        st.z = f2b(acc[i][2] + bv4.z); st.w = f2b(acc[i][3] + bv4.w);
        *reinterpret_cast<ushort4*>(&h[(size_t)(m0 + ty * 4 + i) * En + n0 + tx * 4]) = st;
    }
}

// ---------------- K2a: per-chunk local decayed sums (bf16 h) ----------------
__global__ __launch_bounds__(512) void scan_local_k(const unsigned short* __restrict__ h,
                                                    float* __restrict__ locals) {
    const int c = blockIdx.x, b = blockIdx.y;
    const int e = threadIdx.x;
    const unsigned short* hp = h + ((size_t)(b * Tn + c * CL)) * En + e;
    float s = 0.f;
    for (int t = 0; t < CL; t++) s = (s + b2f(hp[(size_t)t * En])) * INV_DECAY;
    locals[(size_t)(b * NC + c) * En + e] = s;
}

// ---------------- K2b: serial prefix over chunks ----------------
__global__ __launch_bounds__(512) void scan_prefix_k(const float* __restrict__ locals,
                                                     float* __restrict__ Acar) {
    const int b = blockIdx.x;
    const int e = threadIdx.x;
    float invRL = 1.f;
    #pragma unroll
    for (int i = 0; i < CL; i++) invRL *= INV_DECAY;
    float A = 0.f;
    for (int c = 0; c < NC; c++) {
        Acar[(size_t)(b * NC + c) * En + e] = A;
        A = A * invRL + locals[(size_t)(b * NC + c) * En + e];
    }
}

// ---------------- K3: bilinear via MFMA --------------------------------------
// y[t,k] = sum_{i,j} h[t,i] S[t,j] C[hd,k,i,j] + h[t,k]
// GEMM view: A[t, q=(i,j)] = h[t,i]*S[t,j]  (M=tokens, K=1024, step i),
//            B[q, k] = C[hd][k][i][j]  (16B-contiguous in j -> direct B-frag)
// Block: 256 thr (4 waves) x 256 tokens x 1 head. Wave: 4 m-blocks of 16 tokens.
__global__ __launch_bounds__(256) void bilinear_mfma_k(const unsigned short* __restrict__ hb,
                                                       const float* __restrict__ Acar,
                                                       const unsigned short* __restrict__ Cb,
                                                       unsigned short* __restrict__ yb) {
    __shared__ float hs[TCH][36];             // padded: bank-friendly scalar reads
    __shared__ unsigned short Sb[TCH][48];    // bf16 S, 96B rows (16B aligned)

    const int hd = blockIdx.y;
    const int chunkbase = blockIdx.x * TCH;   // flat token index (b*Tn + t)
    const int b = chunkbase >> 11;            // / Tn
    const int c0 = (chunkbase & (Tn - 1)) >> 6; // starting 64-token scan chunk
    const int tid = threadIdx.x;

    // ---- stage h (this head's 32 channels, 256 tokens) as f32 into LDS ----
    {
        const unsigned short* hrow = hb + (size_t)(chunkbase + tid) * En + hd * Dn;
        #pragma unroll
        for (int q = 0; q < 4; q++) {
            u16x8 v = *reinterpret_cast<const u16x8*>(hrow + q * 8);
            #pragma unroll
            for (int e = 0; e < 8; e++) hs[tid][q * 8 + e] = b2f(v[e]);
        }
    }
    __syncthreads();

    // ---- recompute S from carries: 4 sub-chunks x 32 channels ----
    if (tid < 128) {
        const int sc = tid >> 5, ch = tid & 31;
        float s = Acar[(size_t)(b * NC + c0 + sc) * En + hd * Dn + ch];
        const int t0 = sc * 64;
        for (int t = 0; t < 64; t++) {
            Sb[t0 + t][ch] = f2b(s);
            s = (s + hs[t0 + t][ch]) * INV_DECAY;
        }
    }
    __syncthreads();

    // ---- MFMA main loop ----
    const int wid  = tid >> 6;
    const int lane = tid & 63;
    const int tloc = lane & 15;      // A row within m-block / D col (n)
    const int kgrp = lane >> 4;      // k-group
    const int j0   = kgrp * 8;

    const unsigned short* bp0 = Cb + (size_t)hd * (Dn * Dn * Dn)
                              + (size_t)tloc * (Dn * Dn) + j0;          // nt=0
    const unsigned short* bp1 = bp0 + 16 * (Dn * Dn);                   // nt=1

    #pragma unroll
    for (int m = 0; m < 4; m++) {
        const int trow = wid * 64 + m * 16 + tloc;
        // S vector for this token row (fixed across K-steps)
        bf16x8 sv = *reinterpret_cast<const bf16x8*>(&Sb[trow][j0]);
        float sf[8];
        #pragma unroll
        for (int e = 0; e < 8; e++) sf[e] = b2f((unsigned short)sv[e]);

        f32x4 acc0 = {0.f, 0.f, 0.f, 0.f};
        f32x4 acc1 = {0.f, 0.f, 0.f, 0.f};

        #pragma unroll
        for (int i = 0; i < Dn; i++) {
            float hsc = hs[trow][i];
            bf16x8 a;
            #pragma unroll
            for (int e = 0; e < 8; e++) a[e] = (short)f2b(hsc * sf[e]);
            bf16x8 b0 = *reinterpret_cast<const bf16x8*>(bp0 + i * Dn);
            bf16x8 b1 = *reinterpret_cast<const bf16x8*>(bp1 + i * Dn);
            acc0 = __builtin_amdgcn_mfma_f32_16x16x32_bf16(a, b0, acc0, 0, 0, 0);
            acc1 = __builtin_amdgcn_mfma_f32_16x16x32_bf16(a, b1, acc1, 0, 0, 0);
        }

        // ---- epilogue: D layout col=lane&15, row=(lane>>4)*4+reg ----
        #pragma unroll
        for (int nt = 0; nt < 2; nt++) {
            f32x4 acc = nt ? acc1 : acc0;
            const int kcol = nt * 16 + tloc;
            #pragma unroll
            for (int r = 0; r < 4; r++) {
                const int tokr = wid * 64 + m * 16 + kgrp * 4 + r;
                float y = acc[r] + hs[tokr][kcol];
                yb[(size_t)(chunkbase + tokr) * En + hd * Dn + kcol] = f2b(y);
            }
        }
    }
}

// ---------------- K4: LayerNorm over E=512 (bf16 in, f32 out) ----------------
__global__ __launch_bounds__(256) void ln_k(const unsigned short* __restrict__ y,
                                            const float* __restrict__ gamma,
                                            const float* __restrict__ beta,
                                            float* __restrict__ out) {
    const int row = blockIdx.x * 4 + (threadIdx.x >> 6);
    const int lane = threadIdx.x & 63;
    const unsigned short* yp = y + (size_t)row * En;
    u16x8 v = reinterpret_cast<const u16x8*>(yp)[lane];
    float f[8];
    float s = 0.f, s2 = 0.f;
    #pragma unroll
    for (int e = 0; e < 8; e++) {
        f[e] = b2f(v[e]);
        s += f[e]; s2 += f[e] * f[e];
    }
    #pragma unroll
    for (int off = 1; off < 64; off <<= 1) {
        s  += __shfl_xor(s, off);
        s2 += __shfl_xor(s2, off);
    }
    const float mu = s * (1.f / En);
    const float var = s2 * (1.f / En) - mu * mu;
    const float rs = rsqrtf(var + 1e-3f);
    const int cbase = lane * 8;
    float4 g0 = reinterpret_cast<const float4*>(&gamma[cbase])[0];
    float4 g1 = reinterpret_cast<const float4*>(&gamma[cbase])[1];
    float4 b0 = reinterpret_cast<const float4*>(&beta[cbase])[0];
    float4 b1 = reinterpret_cast<const float4*>(&beta[cbase])[1];
    float4 o0, o1;
    o0.x = (f[0] - mu) * rs * g0.x + b0.x; o0.y = (f[1] - mu) * rs * g0.y + b0.y;
    o0.z = (f[2] - mu) * rs * g0.z + b0.z; o0.w = (f[3] - mu) * rs * g0.w + b0.w;
    o1.x = (f[4] - mu) * rs * g1.x + b1.x; o1.y = (f[5] - mu) * rs * g1.y + b1.y;
    o1.z = (f[6] - mu) * rs * g1.z + b1.z; o1.w = (f[7] - mu) * rs * g1.w + b1.w;
    float* op = out + (size_t)row * En;
    reinterpret_cast<float4*>(op)[lane * 2]     = o0;
    reinterpret_cast<float4*>(op)[lane * 2 + 1] = o1;
}

extern "C" void kernel_launch(void* const* d_in, const int* in_sizes, int n_in,
                              void* d_out, int out_size, void* d_ws, size_t ws_size,
                              hipStream_t stream) {
    const float* x     = (const float*)d_in[0];
    const float* W     = (const float*)d_in[1];
    const float* bias  = (const float*)d_in[2];
    const float* C     = (const float*)d_in[3];
    const float* gamma = (const float*)d_in[4];
    const float* beta  = (const float*)d_in[5];
    float* out = (float*)d_out;

    // ws layout: hb bf16 [16384*512] | yb bf16 [16384*512] | locals f32 | Acar f32 | Cb bf16
    unsigned short* hb = (unsigned short*)d_ws;
    unsigned short* yb = hb + (size_t)Bn * Tn * En;
    float* locals = (float*)(yb + (size_t)Bn * Tn * En);
    float* Acar   = locals + (size_t)Bn * NC * En;
    unsigned short* Cbf = (unsigned short*)(Acar + (size_t)Bn * NC * En);
    // total ~34 MiB

    cvtC_k<<<(Hn * Dn * Dn * Dn) / (256 * 8), 256, 0, stream>>>(C, Cbf);
    gemm_k<<<dim3((Bn * Tn) / BM, En / BN), 256, 0, stream>>>(x, W, bias, hb);
    scan_local_k<<<dim3(NC, Bn), 512, 0, stream>>>(hb, locals);
    scan_prefix_k<<<Bn, 512, 0, stream>>>(locals, Acar);
    bilinear_mfma_k<<<dim3((Bn * Tn) / TCH, Hn), 256, 0, stream>>>(hb, Acar, Cbf, yb);
    ln_k<<<(Bn * Tn) / 4, 256, 0, stream>>>(yb, gamma, beta, out);
}

// Round 3
// 96.913 us; speedup vs baseline: 4.7995x; 2.7446x over previous
//
#include <hip/hip_runtime.h>
#include <hip/hip_bf16.h>

// Problem constants
#define Bn 8
#define Tn 2048
#define En 512
#define Hn 16
#define Dn 32
#define NC 32          // scan chunks
#define CL 64          // chunk length (Tn/NC)
#define TCH 256        // tokens per bilinear block
#define INV_DECAY (1.0f/1.2f)

typedef __attribute__((ext_vector_type(8))) short  bf16x8;  // 8 bf16 (4 VGPRs)
typedef __attribute__((ext_vector_type(4))) float  f32x4;
typedef __attribute__((ext_vector_type(8))) unsigned short u16x8;

__device__ __forceinline__ unsigned short f2b(float f) {
    __hip_bfloat16 h = __float2bfloat16(f);   // RNE
    return *reinterpret_cast<unsigned short*>(&h);
}
__device__ __forceinline__ float b2f(unsigned short u) {
    union { unsigned int i; float f; } c; c.i = ((unsigned int)u) << 16; return c.f;
}

// ---------------- K0a: C fp32 -> bf16 (1MB, L2-resident MFMA B operand) ------
__global__ __launch_bounds__(256) void cvtC_k(const float* __restrict__ C,
                                              unsigned short* __restrict__ Cb) {
    int idx = blockIdx.x * 256 + threadIdx.x;   // 8 elems per thread
    const float4* p = reinterpret_cast<const float4*>(C) + (size_t)idx * 2;
    float4 a = p[0], b = p[1];
    u16x8 st;
    st[0]=f2b(a.x); st[1]=f2b(a.y); st[2]=f2b(a.z); st[3]=f2b(a.w);
    st[4]=f2b(b.x); st[5]=f2b(b.y); st[6]=f2b(b.z); st[7]=f2b(b.w);
    *reinterpret_cast<u16x8*>(Cb + (size_t)idx * 8) = st;
}

// ---------------- K0b: W[k][n] f32 -> Wt[n][k] bf16 (transpose for B-frags) --
__global__ __launch_bounds__(256) void cvtWt_k(const float* __restrict__ W,
                                               unsigned short* __restrict__ Wt) {
    __shared__ float tile[32][33];
    const int kb = blockIdx.x * 32, nb = blockIdx.y * 32;
    const int tx = threadIdx.x & 31, ty = threadIdx.x >> 5;   // ty 0..7
    #pragma unroll
    for (int j = 0; j < 4; j++)
        tile[ty + 8 * j][tx] = W[(size_t)(kb + ty + 8 * j) * En + nb + tx];
    __syncthreads();
    #pragma unroll
    for (int j = 0; j < 4; j++)
        Wt[(size_t)(nb + ty + 8 * j) * En + kb + tx] = f2b(tile[tx][ty + 8 * j]);
}

// ---------------- K1: h = x @ W + b  (bf16 MFMA GEMM, f32 accumulate) --------
// M=16384 N=512 K=512. Tile 128x64x32, 256 thr (4 waves, 2x2 wave grid).
__global__ __launch_bounds__(256) void gemm_mfma_k(const float* __restrict__ x,
                                                   const unsigned short* __restrict__ Wt,
                                                   const float* __restrict__ bias,
                                                   unsigned short* __restrict__ h) {
    __shared__ unsigned short As[128][40];   // 10240 B, pad-40 rows (80B)
    __shared__ unsigned short Bs[64][40];    // 5120 B
    const int m0 = blockIdx.x * 128, n0 = blockIdx.y * 64;
    const int tid = threadIdx.x;
    const int wid = tid >> 6, lane = tid & 63;
    const int tloc = lane & 15, kgrp = lane >> 4;
    const int wr = wid >> 1, wc = wid & 1;

    // staging maps
    const int ar = tid >> 1, ah = (tid & 1) * 16;   // A: 2 thr/row, 16 f32 each
    const int brr = tid >> 2, bq = (tid & 3) * 8;   // B: 4 thr/row, 8 bf16 each

    f32x4 acc[4][2] = {};

    for (int k0 = 0; k0 < En; k0 += 32) {
        // global loads to regs
        const float* xp = &x[(size_t)(m0 + ar) * En + k0 + ah];
        float4 a0 = reinterpret_cast<const float4*>(xp)[0];
        float4 a1 = reinterpret_cast<const float4*>(xp)[1];
        float4 a2 = reinterpret_cast<const float4*>(xp)[2];
        float4 a3 = reinterpret_cast<const float4*>(xp)[3];
        u16x8 bv = *reinterpret_cast<const u16x8*>(&Wt[(size_t)(n0 + brr) * En + k0 + bq]);
        __syncthreads();
        u16x8 w0, w1;
        w0[0]=f2b(a0.x); w0[1]=f2b(a0.y); w0[2]=f2b(a0.z); w0[3]=f2b(a0.w);
        w0[4]=f2b(a1.x); w0[5]=f2b(a1.y); w0[6]=f2b(a1.z); w0[7]=f2b(a1.w);
        w1[0]=f2b(a2.x); w1[1]=f2b(a2.y); w1[2]=f2b(a2.z); w1[3]=f2b(a2.w);
        w1[4]=f2b(a3.x); w1[5]=f2b(a3.y); w1[6]=f2b(a3.z); w1[7]=f2b(a3.w);
        *reinterpret_cast<u16x8*>(&As[ar][ah])     = w0;
        *reinterpret_cast<u16x8*>(&As[ar][ah + 8]) = w1;
        *reinterpret_cast<u16x8*>(&Bs[brr][bq])    = bv;
        __syncthreads();

        bf16x8 afr[4], bfr[2];
        #pragma unroll
        for (int m = 0; m < 4; m++)
            afr[m] = *reinterpret_cast<const bf16x8*>(&As[wr * 64 + m * 16 + tloc][kgrp * 8]);
        #pragma unroll
        for (int n = 0; n < 2; n++)
            bfr[n] = *reinterpret_cast<const bf16x8*>(&Bs[wc * 32 + n * 16 + tloc][kgrp * 8]);
        #pragma unroll
        for (int m = 0; m < 4; m++)
            #pragma unroll
            for (int n = 0; n < 2; n++)
                acc[m][n] = __builtin_amdgcn_mfma_f32_16x16x32_bf16(afr[m], bfr[n], acc[m][n], 0, 0, 0);
    }

    // epilogue: +bias, store bf16
    #pragma unroll
    for (int n = 0; n < 2; n++) {
        const int col = n0 + wc * 32 + n * 16 + tloc;
        const float bcol = bias[col];
        #pragma unroll
        for (int m = 0; m < 4; m++)
            #pragma unroll
            for (int r = 0; r < 4; r++) {
                const int row = m0 + wr * 64 + m * 16 + kgrp * 4 + r;
                h[(size_t)row * En + col] = f2b(acc[m][n][r] + bcol);
            }
    }
}

// ---------------- K2a: per-chunk local decayed sums (bf16 h) ----------------
__global__ __launch_bounds__(512) void scan_local_k(const unsigned short* __restrict__ h,
                                                    float* __restrict__ locals) {
    const int c = blockIdx.x, b = blockIdx.y;
    const int e = threadIdx.x;
    const unsigned short* hp = h + ((size_t)(b * Tn + c * CL)) * En + e;
    float s = 0.f;
    for (int t = 0; t < CL; t++) s = (s + b2f(hp[(size_t)t * En])) * INV_DECAY;
    locals[(size_t)(b * NC + c) * En + e] = s;
}

// ---------------- K2b: serial prefix over chunks ----------------
__global__ __launch_bounds__(512) void scan_prefix_k(const float* __restrict__ locals,
                                                     float* __restrict__ Acar) {
    const int b = blockIdx.x;
    const int e = threadIdx.x;
    float invRL = 1.f;
    #pragma unroll
    for (int i = 0; i < CL; i++) invRL *= INV_DECAY;
    float A = 0.f;
    for (int c = 0; c < NC; c++) {
        Acar[(size_t)(b * NC + c) * En + e] = A;
        A = A * invRL + locals[(size_t)(b * NC + c) * En + e];
    }
}

// ---------------- K2c: emit S (bf16) for every token ------------------------
__global__ __launch_bounds__(512) void scan_emit_k(const unsigned short* __restrict__ h,
                                                   const float* __restrict__ Acar,
                                                   unsigned short* __restrict__ Sg) {
    const int c = blockIdx.x, b = blockIdx.y;
    const int e = threadIdx.x;
    float s = Acar[(size_t)(b * NC + c) * En + e];
    const size_t base = ((size_t)(b * Tn + c * CL)) * En + e;
    for (int t = 0; t < CL; t++) {
        Sg[base + (size_t)t * En] = f2b(s);
        s = (s + b2f(h[base + (size_t)t * En])) * INV_DECAY;
    }
}

// ---------------- K3: bilinear via MFMA (i-outer, 8 indep acc chains) --------
// y[t,k] = sum_i h[t,i] * (sum_j S[t,j] C[hd,k,i,j]) + h[t,k], in-place on h.
__global__ __launch_bounds__(256) void bilinear2_k(unsigned short* __restrict__ hio,
                                                   const unsigned short* __restrict__ Sg,
                                                   const unsigned short* __restrict__ Cb) {
    __shared__ unsigned short hsb[TCH][40];   // 20480 B

    const int hd = blockIdx.y;
    const int chunkbase = blockIdx.x * TCH;
    const int tid = threadIdx.x;
    const int wid = tid >> 6, lane = tid & 63;
    const int tloc = lane & 15, kgrp = lane >> 4;
    const int j0 = kgrp * 8;

    // stage h (this head's 32 channels) as bf16
    {
        const unsigned short* hrow = hio + (size_t)(chunkbase + tid) * En + hd * Dn;
        #pragma unroll
        for (int q = 0; q < 4; q++)
            *reinterpret_cast<u16x8*>(&hsb[tid][q * 8]) =
                *reinterpret_cast<const u16x8*>(hrow + q * 8);
    }
    __syncthreads();

    // S fragments: fixed per (m) across the whole i-loop
    float sf[4][8];
    #pragma unroll
    for (int m = 0; m < 4; m++) {
        const int trow = wid * 64 + m * 16 + tloc;
        u16x8 sv = *reinterpret_cast<const u16x8*>(
            Sg + (size_t)(chunkbase + trow) * En + hd * Dn + j0);
        #pragma unroll
        for (int e = 0; e < 8; e++) sf[m][e] = b2f(sv[e]);
    }

    f32x4 acc[4][2] = {};
    const unsigned short* bp = Cb + (size_t)hd * (Dn * Dn * Dn)
                             + (size_t)tloc * (Dn * Dn) + j0;

    #pragma unroll 4
    for (int i = 0; i < Dn; i++) {
        bf16x8 b0 = *reinterpret_cast<const bf16x8*>(bp + i * Dn);
        bf16x8 b1 = *reinterpret_cast<const bf16x8*>(bp + 16 * (Dn * Dn) + i * Dn);
        #pragma unroll
        for (int m = 0; m < 4; m++) {
            const float hsc = b2f(hsb[wid * 64 + m * 16 + tloc][i]);
            bf16x8 a;
            #pragma unroll
            for (int e = 0; e < 8; e++) a[e] = (short)f2b(hsc * sf[m][e]);
            acc[m][0] = __builtin_amdgcn_mfma_f32_16x16x32_bf16(a, b0, acc[m][0], 0, 0, 0);
            acc[m][1] = __builtin_amdgcn_mfma_f32_16x16x32_bf16(a, b1, acc[m][1], 0, 0, 0);
        }
    }

    // epilogue: +residual, in-place store (block owns these (token,channel) slots)
    #pragma unroll
    for (int m = 0; m < 4; m++)
        #pragma unroll
        for (int nt = 0; nt < 2; nt++) {
            const int kcol = nt * 16 + tloc;
            #pragma unroll
            for (int r = 0; r < 4; r++) {
                const int tokr = wid * 64 + m * 16 + kgrp * 4 + r;
                float y = acc[m][nt][r] + b2f(hsb[tokr][kcol]);
                hio[(size_t)(chunkbase + tokr) * En + hd * Dn + kcol] = f2b(y);
            }
        }
}

// ---------------- K4: LayerNorm over E=512 (bf16 in, f32 out) ----------------
__global__ __launch_bounds__(256) void ln_k(const unsigned short* __restrict__ y,
                                            const float* __restrict__ gamma,
                                            const float* __restrict__ beta,
                                            float* __restrict__ out) {
    const int row = blockIdx.x * 4 + (threadIdx.x >> 6);
    const int lane = threadIdx.x & 63;
    const unsigned short* yp = y + (size_t)row * En;
    u16x8 v = reinterpret_cast<const u16x8*>(yp)[lane];
    float f[8];
    float s = 0.f, s2 = 0.f;
    #pragma unroll
    for (int e = 0; e < 8; e++) {
        f[e] = b2f(v[e]);
        s += f[e]; s2 += f[e] * f[e];
    }
    #pragma unroll
    for (int off = 1; off < 64; off <<= 1) {
        s  += __shfl_xor(s, off);
        s2 += __shfl_xor(s2, off);
    }
    const float mu = s * (1.f / En);
    const float var = s2 * (1.f / En) - mu * mu;
    const float rs = rsqrtf(var + 1e-3f);
    const int cbase = lane * 8;
    float4 g0 = reinterpret_cast<const float4*>(&gamma[cbase])[0];
    float4 g1 = reinterpret_cast<const float4*>(&gamma[cbase])[1];
    float4 b0 = reinterpret_cast<const float4*>(&beta[cbase])[0];
    float4 b1 = reinterpret_cast<const float4*>(&beta[cbase])[1];
    float4 o0, o1;
    o0.x = (f[0] - mu) * rs * g0.x + b0.x; o0.y = (f[1] - mu) * rs * g0.y + b0.y;
    o0.z = (f[2] - mu) * rs * g0.z + b0.z; o0.w = (f[3] - mu) * rs * g0.w + b0.w;
    o1.x = (f[4] - mu) * rs * g1.x + b1.x; o1.y = (f[5] - mu) * rs * g1.y + b1.y;
    o1.z = (f[6] - mu) * rs * g1.z + b1.z; o1.w = (f[7] - mu) * rs * g1.w + b1.w;
    float* op = out + (size_t)row * En;
    reinterpret_cast<float4*>(op)[lane * 2]     = o0;
    reinterpret_cast<float4*>(op)[lane * 2 + 1] = o1;
}

extern "C" void kernel_launch(void* const* d_in, const int* in_sizes, int n_in,
                              void* d_out, int out_size, void* d_ws, size_t ws_size,
                              hipStream_t stream) {
    const float* x     = (const float*)d_in[0];
    const float* W     = (const float*)d_in[1];
    const float* bias  = (const float*)d_in[2];
    const float* C     = (const float*)d_in[3];
    const float* gamma = (const float*)d_in[4];
    const float* beta  = (const float*)d_in[5];
    float* out = (float*)d_out;

    // ws layout: hb bf16 16MB | Sg bf16 16MB | Cb bf16 1MB | Wt bf16 0.5MB
    //          | locals f32 0.5MB | Acar f32 0.5MB   (~34.5MB total)
    unsigned short* hb  = (unsigned short*)d_ws;
    unsigned short* Sg  = hb + (size_t)Bn * Tn * En;
    unsigned short* Cbf = Sg + (size_t)Bn * Tn * En;
    unsigned short* Wt  = Cbf + (size_t)Hn * Dn * Dn * Dn;
    float* locals = (float*)(Wt + (size_t)En * En);
    float* Acar   = locals + (size_t)Bn * NC * En;

    cvtC_k<<<(Hn * Dn * Dn * Dn) / (256 * 8), 256, 0, stream>>>(C, Cbf);
    cvtWt_k<<<dim3(En / 32, En / 32), 256, 0, stream>>>(W, Wt);
    gemm_mfma_k<<<dim3((Bn * Tn) / 128, En / 64), 256, 0, stream>>>(x, Wt, bias, hb);
    scan_local_k<<<dim3(NC, Bn), 512, 0, stream>>>(hb, locals);
    scan_prefix_k<<<Bn, 512, 0, stream>>>(locals, Acar);
    scan_emit_k<<<dim3(NC, Bn), 512, 0, stream>>>(hb, Acar, Sg);
    bilinear2_k<<<dim3((Bn * Tn) / TCH, Hn), 256, 0, stream>>>(hb, Sg, Cbf);
    ln_k<<<(Bn * Tn) / 4, 256, 0, stream>>>(hb, gamma, beta, out);
}